// Round 10
// baseline (526.060 us; speedup 1.0000x reference)
//
#include <hip/hip_runtime.h>
#include <hip/hip_bf16.h>

typedef __bf16 bf16;
typedef __attribute__((ext_vector_type(8))) __bf16 bf16x8;
typedef __attribute__((ext_vector_type(4))) __bf16 bf16x4;
typedef __attribute__((ext_vector_type(2))) __bf16 bf16x2;
typedef __attribute__((ext_vector_type(4))) float f32x4;

#define NH 16
#define NKV 4
#define ROPE_DIM 64
#define NOPE_DIM 128
#define V_DIM 128
#define QK_DIM 192
#define TT 2048
#define BB 2
#define MM 4096   // B*T

#define QK_SCALE 0.07216878364870323f   // 1/sqrt(192), folded into q epilogue

// ---------------- async global->LDS (16B per lane) ----------------
__device__ __forceinline__ void gload16(const bf16* g, bf16* l) {
    __builtin_amdgcn_global_load_lds(
        (const __attribute__((address_space(1))) void*)g,
        (__attribute__((address_space(3))) void*)l, 16, 0, 0);
}

// ---------------- fused prep: 8 weight transposes + rope table + x convert ----
struct PrepArgs {
    const float* wsrc[8];
    bf16* wdst[8];
    const float* x;
    bf16* xb;
    float* ct;
    float* st;
};

__global__ __launch_bounds__(256) void k_prep(PrepArgs a) {
    // weight table: {Wkvd, Wqd, Wkn, Wkr, Wv, Wqn, Wqr, Wo}
    constexpr int WR[8] = {2048, 2048, 512, 512, 512, 1536, 1536, 2048};
    constexpr int WC[8] = {512, 1536, 512, 256, 512, 2048, 1024, 2048};
    const int bid = blockIdx.x;
    if (bid < 13440) {
        // sequential prefix search; `w == i` guard (R5 bug fix).
        int w = 0, base = 0;
        #pragma unroll
        for (int i = 0; i < 8; i++) {
            int t = (WC[i] >> 5) * (WR[i] >> 5);
            if (w == i && bid >= base + t) { base += t; w = i + 1; }
        }
        const int local = bid - base;
        const int R = WR[w], C = WC[w];
        const int tilesX = C >> 5;
        const int tyt = local / tilesX, txt = local - tyt * tilesX;
        const int c0 = txt * 32, r0 = tyt * 32;
        const float* s = a.wsrc[w];
        bf16* d = a.wdst[w];
        __shared__ float tile[32][33];
        int tx = threadIdx.x & 31, ty = threadIdx.x >> 5;
        #pragma unroll
        for (int rr = ty; rr < 32; rr += 8)
            tile[rr][tx] = s[(size_t)(r0 + rr) * C + c0 + tx];
        __syncthreads();
        #pragma unroll
        for (int q = threadIdx.x; q < 512; q += 256) {
            int ccq = q >> 4, pr = (q & 15) << 1;
            bf16x2 v;
            v[0] = (bf16)tile[pr][ccq];
            v[1] = (bf16)tile[pr + 1][ccq];
            *(bf16x2*)&d[(size_t)(c0 + ccq) * R + r0 + pr] = v;
        }
    } else if (bid < 13696) {
        int idx = (bid - 13440) * 256 + threadIdx.x;   // [0, 65536)
        int t = idx >> 5, i = idx & 31;
        float theta = powf(10000.f, -(float)(2 * i) / 64.f);
        float ang = (float)t * theta;
        a.ct[idx] = cosf(ang);
        a.st[idx] = sinf(ang);
    } else {
        int i = (bid - 13696) * 256 + threadIdx.x;     // float4 index
        float4 v = *(const float4*)(a.x + (size_t)i * 4);
        bf16* o = a.xb + (size_t)i * 4;
        o[0] = (bf16)v.x; o[1] = (bf16)v.y; o[2] = (bf16)v.z; o[3] = (bf16)v.w;
    }
}

// ---------------- bf16 GEMM body: C = A * Bt^T, 128x128 tile, 2-phase dbuf ----
// EPI: 0 = bf16 linear, 1 = f32 linear,
//      2 = KV epilogue (KA with rope + VT transpose), 3 = Q epilogue (rope+scale)
template<int EPI>
__device__ __forceinline__ void gemm_body(
        bf16 (*As)[128 * 32], bf16 (*Bs)[128 * 32], int bx, int by,
        const bf16* __restrict__ A, int lda,
        const bf16* __restrict__ Bt, int ldb,
        void* __restrict__ Cv, int ldc, int K,
        const float* __restrict__ ct, const float* __restrict__ st,
        bf16* __restrict__ vt) {
    const int tid = threadIdx.x;
    const int lane = tid & 63;
    const int wid = tid >> 6;
    const int wr = wid >> 1, wc = wid & 1;
    const int g = lane >> 4, c = lane & 15;
    const int m0 = by * 128, n0 = bx * 128;

    f32x4 acc[4][4] = {};
    const int rdswz = (g ^ ((c >> 1) & 3)) * 8;

    auto stage = [&](int buf, int k0) {
        #pragma unroll
        for (int i = 0; i < 2; i++) {
            int ch = tid + 256 * i;
            int row = ch >> 2;
            int kc = (ch & 3) ^ ((ch >> 3) & 3);
            gload16(A + (size_t)(m0 + row) * lda + k0 + kc * 8, &As[buf][ch * 8]);
            gload16(Bt + (size_t)(n0 + row) * ldb + k0 + kc * 8, &Bs[buf][ch * 8]);
        }
    };

    stage(0, 0);
    __syncthreads();
    const int nt = K >> 5;
    for (int t = 0; t < nt; ++t) {
        const int cur = t & 1;
        if (t + 1 < nt) stage(cur ^ 1, (t + 1) << 5);
        bf16x8 af[4], bfr[4];
        #pragma unroll
        for (int i = 0; i < 4; i++)
            af[i] = *(const bf16x8*)&As[cur][(wr * 64 + i * 16 + c) * 32 + rdswz];
        #pragma unroll
        for (int j = 0; j < 4; j++)
            bfr[j] = *(const bf16x8*)&Bs[cur][(wc * 64 + j * 16 + c) * 32 + rdswz];
        #pragma unroll
        for (int i = 0; i < 4; i++)
            #pragma unroll
            for (int j = 0; j < 4; j++)
                acc[i][j] = __builtin_amdgcn_mfma_f32_16x16x32_bf16(
                    af[i], bfr[j], acc[i][j], 0, 0, 0);
        __syncthreads();
    }

    if constexpr (EPI <= 1) {
        #pragma unroll
        for (int i = 0; i < 4; i++) {
            int row = m0 + wr * 64 + i * 16 + g * 4;
            #pragma unroll
            for (int j = 0; j < 4; j++) {
                int col = n0 + wc * 64 + j * 16 + c;
                #pragma unroll
                for (int r = 0; r < 4; r++) {
                    if (EPI == 1)
                        ((float*)Cv)[(size_t)(row + r) * ldc + col] = acc[i][j][r];
                    else
                        ((bf16*)Cv)[(size_t)(row + r) * ldc + col] = (bf16)acc[i][j][r];
                }
            }
        }
    } else if constexpr (EPI == 2) {
        // cols [0,512)=k_nope, [512,768)=k_rope, [768,1280)=v
        bf16* ka = (bf16*)Cv;
        #pragma unroll
        for (int i = 0; i < 4; i++) {
            int row = m0 + wr * 64 + i * 16 + g * 4;
            int bq = row >> 11, t0 = row & 2047;
            #pragma unroll
            for (int j = 0; j < 4; j++) {
                int col = n0 + wc * 64 + j * 16 + c;
                if (col < 512) {
                    int h = col >> 7, d = col & 127;
                    bf16* dst = ka + ((size_t)(bq * NKV + h) * TT + t0) * QK_DIM + d;
                    #pragma unroll
                    for (int r = 0; r < 4; r++) dst[r * QK_DIM] = (bf16)acc[i][j][r];
                } else if (col < 768) {
                    int cr = col - 512;
                    int h = cr >> 6, dr = cr & 63, ia = dr & 31;
                    float sgn = (dr < 32) ? -1.f : 1.f;
                    bf16* dst = ka + ((size_t)(bq * NKV + h) * TT + t0) * QK_DIM + 128 + dr;
                    #pragma unroll
                    for (int r = 0; r < 4; r++) {
                        float cs = ct[(t0 + r) * 32 + ia], sn = st[(t0 + r) * 32 + ia];
                        dst[r * QK_DIM] = (bf16)(acc[i][j][r] * cs + sgn * acc[i][j ^ 2][r] * sn);
                    }
                } else {
                    int cr = col - 768;
                    int h = cr >> 7, d = cr & 127;
                    bf16x4 pk;
                    #pragma unroll
                    for (int r = 0; r < 4; r++) pk[r] = (bf16)acc[i][j][r];
                    *(bf16x4*)&vt[((size_t)((bq * NKV + h) * V_DIM + d)) * TT + t0] = pk;
                }
            }
        }
    } else {
        // cols [0,2048)=q_nope, [2048,3072)=q_rope; scale folded in
        bf16* qa = (bf16*)Cv;
        #pragma unroll
        for (int i = 0; i < 4; i++) {
            int row = m0 + wr * 64 + i * 16 + g * 4;
            int bq = row >> 11, t0 = row & 2047;
            #pragma unroll
            for (int j = 0; j < 4; j++) {
                int col = n0 + wc * 64 + j * 16 + c;
                if (col < 2048) {
                    int h = col >> 7, d = col & 127;
                    bf16* dst = qa + ((size_t)(bq * NH + h) * TT + t0) * QK_DIM + d;
                    #pragma unroll
                    for (int r = 0; r < 4; r++)
                        dst[r * QK_DIM] = (bf16)(acc[i][j][r] * QK_SCALE);
                } else {
                    int cr = col - 2048;
                    int h = cr >> 6, dr = cr & 63, ia = dr & 31;
                    float sgn = (dr < 32) ? -1.f : 1.f;
                    bf16* dst = qa + ((size_t)(bq * NH + h) * TT + t0) * QK_DIM + 128 + dr;
                    #pragma unroll
                    for (int r = 0; r < 4; r++) {
                        float cs = ct[(t0 + r) * 32 + ia], sn = st[(t0 + r) * 32 + ia];
                        dst[r * QK_DIM] =
                            (bf16)((acc[i][j][r] * cs + sgn * acc[i][j ^ 2][r] * sn) * QK_SCALE);
                    }
                }
            }
        }
    }
}

template<int EPI>
__global__ __launch_bounds__(256) void k_gemm(const bf16* __restrict__ A, int lda,
                                              const bf16* __restrict__ Bt, int ldb,
                                              void* __restrict__ Cv, int ldc, int K,
                                              const float* __restrict__ ct,
                                              const float* __restrict__ st,
                                              bf16* __restrict__ vt) {
    __shared__ __align__(16) bf16 As[2][128 * 32];
    __shared__ __align__(16) bf16 Bs[2][128 * 32];
    gemm_body<EPI>(As, Bs, blockIdx.x, blockIdx.y, A, lda, Bt, ldb, Cv, ldc, K, ct, st, vt);
}

// merged GEMM2 (320 blocks) + GEMM3 (768 blocks): both consume C1 only
__global__ __launch_bounds__(256) void k_gemm23(const bf16* __restrict__ C1,
                                                const bf16* __restrict__ BT2,
                                                const bf16* __restrict__ BT3,
                                                bf16* __restrict__ KA,
                                                bf16* __restrict__ QA,
                                                bf16* __restrict__ VT,
                                                const float* __restrict__ ct,
                                                const float* __restrict__ st) {
    __shared__ __align__(16) bf16 As[2][128 * 32];
    __shared__ __align__(16) bf16 Bs[2][128 * 32];
    const int bid = blockIdx.x;
    if (bid < 320) {
        gemm_body<2>(As, Bs, bid % 10, bid / 10, C1, 2048, BT2, 512, KA, 0, 512, ct, st, VT);
    } else {
        const int b2 = bid - 320;
        gemm_body<3>(As, Bs, b2 % 24, b2 / 24, C1 + 512, 2048, BT3, 1536, QA, 0, 1536,
                     ct, st, nullptr);
    }
}

// ---------------- causal GQA flash attention (swapped-operand, P-in-register) --
// grid (16, B*H); 4 waves x 32 q-rows; 64-key tiles.
// S^T = mfma(K, Q) with K rows PERMUTED at staging: LDS row 16j+4g+r holds
// physical key sigma = 32(j>>1) + 8g + 4(j&1) + r (bijective on [0,64)). Lane
// (g,c)'s S values are then exactly PV's B-fragment keys 32kc+8g+0..7 -> P
// never touches LDS (zero-shuffle). Mask: key = k0+32(j>>1)+8g+4(j&1)+r.
// Fixed-shift softmax: P = exp(S) (shift-invariance; |S|~O(1), masked -> 0).
// R9 post-mortem: NO unions, NO break-in-unrolled-loop — those demoted P to
// scratch (VGPR=84, +100MB spill traffic, 2.7x slower). P packed via
// compile-time element inserts into bf16x8 so SROA keeps it in VGPRs (rule #20).
__global__ __launch_bounds__(256, 3) void k_attn(const bf16* __restrict__ qa,
                                                 const bf16* __restrict__ ka,
                                                 const bf16* __restrict__ vt,
                                                 bf16* __restrict__ out) {
    __shared__ __align__(16) bf16 Klds[64 * QK_DIM];
    __shared__ __align__(16) bf16 Vlds[128 * 64];

    const int tid  = threadIdx.x;
    const int lane = tid & 63;
    const int wid  = tid >> 6;
    const int g = lane >> 4, c = lane & 15;
    const int hsw = c & 7;                 // chunk-xor swizzle key

    const int qi = (blockIdx.y & 16) ? (15 - (int)blockIdx.x) : (int)blockIdx.x;
    const int q0 = qi * 128;
    const int bh = blockIdx.y;
    const int b = bh >> 4, h = bh & 15;
    const int kv = b * NKV + (h >> 2);
    const int qb0 = q0 + wid * 32;

    bf16x8 qf[2][6];
    #pragma unroll
    for (int qs = 0; qs < 2; ++qs) {
        const bf16* qp = qa + ((size_t)bh * TT + qb0 + qs * 16 + c) * QK_DIM + g * 8;
        #pragma unroll
        for (int cc = 0; cc < 6; ++cc) qf[qs][cc] = *(const bf16x8*)(qp + cc * 32);
    }

    f32x4 accO[2][8] = {};
    float l0 = 0.f, l1 = 0.f;

    const bf16* kbase = ka + (size_t)kv * TT * QK_DIM;
    const bf16* vbase = vt + (size_t)kv * V_DIM * TT;

    const int nk = 2 * qi + 2;
    for (int it = 0; it < nk; ++it) {
        const int k0 = it * 64;
        __syncthreads();
        // stage K tile [64][192] with key-permuted source rows
        #pragma unroll
        for (int i = 0; i < 6; ++i) {
            int ch = tid + 256 * i;
            int row = ch / 24, cs = ch % 24;
            int gc = cs ^ (row & 7);
            int jl = row >> 4, gl = (row >> 2) & 3, rl = row & 3;
            int psrc = 32 * (jl >> 1) + 8 * gl + 4 * (jl & 1) + rl;  // sigma(row)
            gload16(kbase + (size_t)(k0 + psrc) * QK_DIM + gc * 8, &Klds[ch * 8]);
        }
        // stage V^T tile [128][64]
        #pragma unroll
        for (int i = 0; i < 4; ++i) {
            int ch = tid + 256 * i;
            int row = ch >> 3, cs = ch & 7;
            int gc = cs ^ (row & 7);
            gload16(vbase + (size_t)row * TT + k0 + gc * 8, &Vlds[ch * 8]);
        }
        __syncthreads();

        if (k0 > qb0 + 15) continue;          // whole wave masked this tile
        const bool a1 = (k0 <= qb0 + 31);     // qs=1 active (a1 => a0)

        // S^T = K * Q^T : s[qs][j][r] = S[key = k0+32(j>>1)+8g+4(j&1)+r][q]
        f32x4 s0[4] = {}, s1[4] = {};
        #pragma unroll
        for (int cc = 0; cc < 6; ++cc) {
            #pragma unroll
            for (int j = 0; j < 4; ++j) {
                bf16x8 kf = *(const bf16x8*)&Klds[(j * 16 + c) * QK_DIM +
                                                  ((4 * cc + g) ^ hsw) * 8];
                s0[j] = __builtin_amdgcn_mfma_f32_16x16x32_bf16(kf, qf[0][cc], s0[j], 0, 0, 0);
                s1[j] = __builtin_amdgcn_mfma_f32_16x16x32_bf16(kf, qf[1][cc], s1[j], 0, 0, 0);
            }
        }

        // fixed-shift softmax; P packed by compile-time inserts (registers only)
        const bool diag = (k0 + 63 > qb0);    // qb0 is the smaller q-base
        bf16x8 pf0[2], pf1[2];
        {   // qs = 0 (always active here)
            if (diag) {
                #pragma unroll
                for (int j = 0; j < 4; ++j) {
                    const int kb2 = k0 + 32 * (j >> 1) + 4 * (j & 1) + 8 * g;
                    #pragma unroll
                    for (int r = 0; r < 4; ++r)
                        if (kb2 + r > qb0 + c) s0[j][r] = -1e30f;
                }
            }
            float ps = 0.f;
            #pragma unroll
            for (int j = 0; j < 4; ++j)
                #pragma unroll
                for (int r = 0; r < 4; ++r) {
                    float e = __expf(s0[j][r]);
                    ps += e;
                    pf0[j >> 1][(j & 1) * 4 + r] = (bf16)e;
                }
            ps += __shfl_xor(ps, 16, 64);
            ps += __shfl_xor(ps, 32, 64);
            l0 += ps;
        }
        if (a1) {   // qs = 1
            const int qb = qb0 + 16;
            if (k0 + 63 > qb) {
                #pragma unroll
                for (int j = 0; j < 4; ++j) {
                    const int kb2 = k0 + 32 * (j >> 1) + 4 * (j & 1) + 8 * g;
                    #pragma unroll
                    for (int r = 0; r < 4; ++r)
                        if (kb2 + r > qb + c) s1[j][r] = -1e30f;
                }
            }
            float ps = 0.f;
            #pragma unroll
            for (int j = 0; j < 4; ++j)
                #pragma unroll
                for (int r = 0; r < 4; ++r) {
                    float e = __expf(s1[j][r]);
                    ps += e;
                    pf1[j >> 1][(j & 1) * 4 + r] = (bf16)e;
                }
            ps += __shfl_xor(ps, 16, 64);
            ps += __shfl_xor(ps, 32, 64);
            l1 += ps;
        }

        // O^T += V^T * P^T ; P fragments live in VGPRs (lane-local)
        if (a1) {
            #pragma unroll
            for (int kc = 0; kc < 2; ++kc)
                #pragma unroll
                for (int nj = 0; nj < 8; ++nj) {
                    bf16x8 vf = *(const bf16x8*)&Vlds[(nj * 16 + c) * 64 +
                                                      ((4 * kc + g) ^ hsw) * 8];
                    accO[0][nj] = __builtin_amdgcn_mfma_f32_16x16x32_bf16(vf, pf0[kc], accO[0][nj], 0, 0, 0);
                    accO[1][nj] = __builtin_amdgcn_mfma_f32_16x16x32_bf16(vf, pf1[kc], accO[1][nj], 0, 0, 0);
                }
        } else {
            #pragma unroll
            for (int kc = 0; kc < 2; ++kc)
                #pragma unroll
                for (int nj = 0; nj < 8; ++nj) {
                    bf16x8 vf = *(const bf16x8*)&Vlds[(nj * 16 + c) * 64 +
                                                      ((4 * kc + g) ^ hsw) * 8];
                    accO[0][nj] = __builtin_amdgcn_mfma_f32_16x16x32_bf16(vf, pf0[kc], accO[0][nj], 0, 0, 0);
                }
        }
    }

    // epilogue: out[b*T+q][h*128 + d], d = nj*16 + g*4 + r, q = qb0+qs*16+c
    #pragma unroll
    for (int qs = 0; qs < 2; ++qs) {
        float inv = 1.f / (qs ? l1 : l0);
        size_t rowoff = ((size_t)(b * TT + qb0 + qs * 16 + c)) * (NH * V_DIM) + h * V_DIM;
        #pragma unroll
        for (int nj = 0; nj < 8; ++nj) {
            bf16x4 o;
            #pragma unroll
            for (int r = 0; r < 4; ++r) o[r] = (bf16)(accO[qs][nj][r] * inv);
            *(bf16x4*)&out[rowoff + nj * 16 + g * 4] = o;
        }
    }
}

// ------------------------------------------------------------------
extern "C" void kernel_launch(void* const* d_in, const int* in_sizes, int n_in,
                              void* d_out, int out_size, void* d_ws, size_t ws_size,
                              hipStream_t stream) {
    const float* x    = (const float*)d_in[0];

    char* p = (char*)d_ws;
    size_t off = 0;
    auto take = [&](size_t elems, size_t esz) -> void* {
        void* r = p + off;
        off += ((elems * esz + 255) / 256) * 256;
        return r;
    };

    bf16* XB  = (bf16*)take((size_t)MM * 2048, 2);       // x bf16
    bf16* BT1 = (bf16*)take((size_t)2048 * 2048, 2);     // [kv_down^T ; q_down^T]
    bf16* BT2 = (bf16*)take((size_t)1280 * 512, 2);      // [k_nope^T ; k_rope^T ; v^T]
    bf16* BT3 = (bf16*)take((size_t)3072 * 1536, 2);     // [q_nope^T ; q_rope^T]
    bf16* BTO = (bf16*)take((size_t)2048 * 2048, 2);     // W_o^T
    bf16* C1  = (bf16*)take((size_t)MM * 2048, 2);       // [kv_c | q_c]
    bf16* QA  = (bf16*)take((size_t)BB * NH * TT * QK_DIM, 2);
    bf16* KA  = (bf16*)take((size_t)BB * NKV * TT * QK_DIM, 2);
    bf16* VT  = (bf16*)take((size_t)BB * NKV * V_DIM * TT, 2);
    bf16* AO  = (bf16*)take((size_t)MM * 2048, 2);       // attention out
    float* CT = (float*)take((size_t)TT * 32, 4);
    float* ST = (float*)take((size_t)TT * 32, 4);
    (void)ws_size; (void)in_sizes; (void)n_in; (void)out_size;

    // --- stage 0: one fused prep kernel ---
    PrepArgs pa;
    pa.wsrc[0] = (const float*)d_in[1]; pa.wdst[0] = BT1;                         // Wkvd
    pa.wsrc[1] = (const float*)d_in[5]; pa.wdst[1] = BT1 + (size_t)512 * 2048;    // Wqd
    pa.wsrc[2] = (const float*)d_in[2]; pa.wdst[2] = BT2;                         // Wkn
    pa.wsrc[3] = (const float*)d_in[3]; pa.wdst[3] = BT2 + (size_t)512 * 512;     // Wkr
    pa.wsrc[4] = (const float*)d_in[4]; pa.wdst[4] = BT2 + (size_t)768 * 512;     // Wv
    pa.wsrc[5] = (const float*)d_in[6]; pa.wdst[5] = BT3;                         // Wqn
    pa.wsrc[6] = (const float*)d_in[7]; pa.wdst[6] = BT3 + (size_t)2048 * 1536;   // Wqr
    pa.wsrc[7] = (const float*)d_in[8]; pa.wdst[7] = BTO;                         // Wo
    pa.x = x; pa.xb = XB; pa.ct = CT; pa.st = ST;
    k_prep<<<21888, 256, 0, stream>>>(pa);

    // --- stage 1: projection GEMMs (RoPE/assembly fused into epilogues) ---
    k_gemm<0><<<dim3(16, 32), 256, 0, stream>>>(XB, 2048, BT1, 2048, C1, 2048, 2048,
                                                nullptr, nullptr, nullptr);
    k_gemm23<<<1088, 256, 0, stream>>>(C1, BT2, BT3, KA, QA, VT, CT, ST);

    // --- stage 2: causal GQA flash attention ---
    k_attn<<<dim3(16, BB * NH), 256, 0, stream>>>(QA, KA, VT, AO);

    // --- stage 3: output projection (f32 out) ---
    k_gemm<1><<<dim3(16, 32), 256, 0, stream>>>(AO, 2048, BTO, 2048, d_out, 2048, 2048,
                                                nullptr, nullptr, nullptr);
}

// Round 12
// 392.843 us; speedup vs baseline: 1.3391x; 1.3391x over previous
//
#include <hip/hip_runtime.h>
#include <hip/hip_bf16.h>

typedef __bf16 bf16;
typedef __attribute__((ext_vector_type(8))) __bf16 bf16x8;
typedef __attribute__((ext_vector_type(4))) __bf16 bf16x4;
typedef __attribute__((ext_vector_type(2))) __bf16 bf16x2;
typedef __attribute__((ext_vector_type(4))) float f32x4;

#define NH 16
#define NKV 4
#define ROPE_DIM 64
#define NOPE_DIM 128
#define V_DIM 128
#define QK_DIM 192
#define TT 2048
#define BB 2
#define MM 4096   // B*T

#define QK_SCALE 0.07216878364870323f   // 1/sqrt(192), folded into q epilogue

// ---------------- async global->LDS (16B per lane) ----------------
__device__ __forceinline__ void gload16(const bf16* g, bf16* l) {
    __builtin_amdgcn_global_load_lds(
        (const __attribute__((address_space(1))) void*)g,
        (__attribute__((address_space(3))) void*)l, 16, 0, 0);
}

// XCD-aware chunked swizzle (T1): nwg % 8 == 0 required (bijective).
__device__ __forceinline__ int xcd_swz(int id, int nwg) {
    int cpx = nwg >> 3;
    return (id & 7) * cpx + (id >> 3);
}

// ---------------- fused prep: 8 weight transposes + rope table + x convert ----
struct PrepArgs {
    const float* wsrc[8];
    bf16* wdst[8];
    const float* x;
    bf16* xb;
    float* ct;
    float* st;
};

__global__ __launch_bounds__(256) void k_prep(PrepArgs a) {
    // weight table: {Wkvd, Wqd, Wkn, Wkr, Wv, Wqn, Wqr, Wo}
    constexpr int WR[8] = {2048, 2048, 512, 512, 512, 1536, 1536, 2048};
    constexpr int WC[8] = {512, 1536, 512, 256, 512, 2048, 1024, 2048};
    const int bid = blockIdx.x;
    if (bid < 13440) {
        // sequential prefix search; `w == i` guard (R5 bug fix).
        int w = 0, base = 0;
        #pragma unroll
        for (int i = 0; i < 8; i++) {
            int t = (WC[i] >> 5) * (WR[i] >> 5);
            if (w == i && bid >= base + t) { base += t; w = i + 1; }
        }
        const int local = bid - base;
        const int R = WR[w], C = WC[w];
        const int tilesX = C >> 5;
        const int tyt = local / tilesX, txt = local - tyt * tilesX;
        const int c0 = txt * 32, r0 = tyt * 32;
        const float* s = a.wsrc[w];
        bf16* d = a.wdst[w];
        __shared__ float tile[32][33];
        int tx = threadIdx.x & 31, ty = threadIdx.x >> 5;
        #pragma unroll
        for (int rr = ty; rr < 32; rr += 8)
            tile[rr][tx] = s[(size_t)(r0 + rr) * C + c0 + tx];
        __syncthreads();
        #pragma unroll
        for (int q = threadIdx.x; q < 512; q += 256) {
            int ccq = q >> 4, pr = (q & 15) << 1;
            bf16x2 v;
            v[0] = (bf16)tile[pr][ccq];
            v[1] = (bf16)tile[pr + 1][ccq];
            *(bf16x2*)&d[(size_t)(c0 + ccq) * R + r0 + pr] = v;
        }
    } else if (bid < 13696) {
        int idx = (bid - 13440) * 256 + threadIdx.x;   // [0, 65536)
        int t = idx >> 5, i = idx & 31;
        float theta = powf(10000.f, -(float)(2 * i) / 64.f);
        float ang = (float)t * theta;
        a.ct[idx] = cosf(ang);
        a.st[idx] = sinf(ang);
    } else {
        int i = (bid - 13696) * 256 + threadIdx.x;     // float4 index
        float4 v = *(const float4*)(a.x + (size_t)i * 4);
        bf16* o = a.xb + (size_t)i * 4;
        o[0] = (bf16)v.x; o[1] = (bf16)v.y; o[2] = (bf16)v.z; o[3] = (bf16)v.w;
    }
}

// ---------------- bf16 GEMM body: C = A * Bt^T, 128x128 tile, 2-phase dbuf ----
// EPI: 0 = bf16 linear, 1 = f32 linear,
//      2 = KV epilogue (KA with rope + VT transpose), 3 = Q epilogue (rope+scale)
template<int EPI>
__device__ __forceinline__ void gemm_body(
        bf16 (*As)[128 * 32], bf16 (*Bs)[128 * 32], int bx, int by,
        const bf16* __restrict__ A, int lda,
        const bf16* __restrict__ Bt, int ldb,
        void* __restrict__ Cv, int ldc, int K,
        const float* __restrict__ ct, const float* __restrict__ st,
        bf16* __restrict__ vt) {
    const int tid = threadIdx.x;
    const int lane = tid & 63;
    const int wid = tid >> 6;
    const int wr = wid >> 1, wc = wid & 1;
    const int g = lane >> 4, c = lane & 15;
    const int m0 = by * 128, n0 = bx * 128;

    f32x4 acc[4][4] = {};
    const int rdswz = (g ^ ((c >> 1) & 3)) * 8;

    auto stage = [&](int buf, int k0) {
        #pragma unroll
        for (int i = 0; i < 2; i++) {
            int ch = tid + 256 * i;
            int row = ch >> 2;
            int kc = (ch & 3) ^ ((ch >> 3) & 3);
            gload16(A + (size_t)(m0 + row) * lda + k0 + kc * 8, &As[buf][ch * 8]);
            gload16(Bt + (size_t)(n0 + row) * ldb + k0 + kc * 8, &Bs[buf][ch * 8]);
        }
    };

    stage(0, 0);
    __syncthreads();
    const int nt = K >> 5;
    for (int t = 0; t < nt; ++t) {
        const int cur = t & 1;
        if (t + 1 < nt) stage(cur ^ 1, (t + 1) << 5);
        bf16x8 af[4], bfr[4];
        #pragma unroll
        for (int i = 0; i < 4; i++)
            af[i] = *(const bf16x8*)&As[cur][(wr * 64 + i * 16 + c) * 32 + rdswz];
        #pragma unroll
        for (int j = 0; j < 4; j++)
            bfr[j] = *(const bf16x8*)&Bs[cur][(wc * 64 + j * 16 + c) * 32 + rdswz];
        #pragma unroll
        for (int i = 0; i < 4; i++)
            #pragma unroll
            for (int j = 0; j < 4; j++)
                acc[i][j] = __builtin_amdgcn_mfma_f32_16x16x32_bf16(
                    af[i], bfr[j], acc[i][j], 0, 0, 0);
        __syncthreads();
    }

    if constexpr (EPI <= 1) {
        #pragma unroll
        for (int i = 0; i < 4; i++) {
            int row = m0 + wr * 64 + i * 16 + g * 4;
            #pragma unroll
            for (int j = 0; j < 4; j++) {
                int col = n0 + wc * 64 + j * 16 + c;
                #pragma unroll
                for (int r = 0; r < 4; r++) {
                    if (EPI == 1)
                        ((float*)Cv)[(size_t)(row + r) * ldc + col] = acc[i][j][r];
                    else
                        ((bf16*)Cv)[(size_t)(row + r) * ldc + col] = (bf16)acc[i][j][r];
                }
            }
        }
    } else if constexpr (EPI == 2) {
        // cols [0,512)=k_nope, [512,768)=k_rope, [768,1280)=v
        bf16* ka = (bf16*)Cv;
        #pragma unroll
        for (int i = 0; i < 4; i++) {
            int row = m0 + wr * 64 + i * 16 + g * 4;
            int bq = row >> 11, t0 = row & 2047;
            #pragma unroll
            for (int j = 0; j < 4; j++) {
                int col = n0 + wc * 64 + j * 16 + c;
                if (col < 512) {
                    int h = col >> 7, d = col & 127;
                    bf16* dst = ka + ((size_t)(bq * NKV + h) * TT + t0) * QK_DIM + d;
                    #pragma unroll
                    for (int r = 0; r < 4; r++) dst[r * QK_DIM] = (bf16)acc[i][j][r];
                } else if (col < 768) {
                    int cr = col - 512;
                    int h = cr >> 6, dr = cr & 63, ia = dr & 31;
                    float sgn = (dr < 32) ? -1.f : 1.f;
                    bf16* dst = ka + ((size_t)(bq * NKV + h) * TT + t0) * QK_DIM + 128 + dr;
                    #pragma unroll
                    for (int r = 0; r < 4; r++) {
                        float cs = ct[(t0 + r) * 32 + ia], sn = st[(t0 + r) * 32 + ia];
                        dst[r * QK_DIM] = (bf16)(acc[i][j][r] * cs + sgn * acc[i][j ^ 2][r] * sn);
                    }
                } else {
                    int cr = col - 768;
                    int h = cr >> 7, d = cr & 127;
                    bf16x4 pk;
                    #pragma unroll
                    for (int r = 0; r < 4; r++) pk[r] = (bf16)acc[i][j][r];
                    *(bf16x4*)&vt[((size_t)((bq * NKV + h) * V_DIM + d)) * TT + t0] = pk;
                }
            }
        }
    } else {
        // cols [0,2048)=q_nope, [2048,3072)=q_rope; scale folded in
        bf16* qa = (bf16*)Cv;
        #pragma unroll
        for (int i = 0; i < 4; i++) {
            int row = m0 + wr * 64 + i * 16 + g * 4;
            int bq = row >> 11, t0 = row & 2047;
            #pragma unroll
            for (int j = 0; j < 4; j++) {
                int col = n0 + wc * 64 + j * 16 + c;
                if (col < 2048) {
                    int h = col >> 7, d = col & 127;
                    bf16* dst = qa + ((size_t)(bq * NH + h) * TT + t0) * QK_DIM + d;
                    #pragma unroll
                    for (int r = 0; r < 4; r++)
                        dst[r * QK_DIM] = (bf16)(acc[i][j][r] * QK_SCALE);
                } else {
                    int cr = col - 2048;
                    int h = cr >> 6, dr = cr & 63, ia = dr & 31;
                    float sgn = (dr < 32) ? -1.f : 1.f;
                    bf16* dst = qa + ((size_t)(bq * NH + h) * TT + t0) * QK_DIM + 128 + dr;
                    #pragma unroll
                    for (int r = 0; r < 4; r++) {
                        float cs = ct[(t0 + r) * 32 + ia], sn = st[(t0 + r) * 32 + ia];
                        dst[r * QK_DIM] =
                            (bf16)((acc[i][j][r] * cs + sgn * acc[i][j ^ 2][r] * sn) * QK_SCALE);
                    }
                }
            }
        }
    }
}

// 1D grid + XCD swizzle; nbx = tiles along N, nwg = total blocks (mult of 8)
template<int EPI>
__global__ __launch_bounds__(256) void k_gemm(const bf16* __restrict__ A, int lda,
                                              const bf16* __restrict__ Bt, int ldb,
                                              void* __restrict__ Cv, int ldc, int K,
                                              const float* __restrict__ ct,
                                              const float* __restrict__ st,
                                              bf16* __restrict__ vt,
                                              int nbx, int nwg) {
    __shared__ __align__(16) bf16 As[2][128 * 32];
    __shared__ __align__(16) bf16 Bs[2][128 * 32];
    const int id = xcd_swz(blockIdx.x, nwg);
    gemm_body<EPI>(As, Bs, id % nbx, id / nbx, A, lda, Bt, ldb, Cv, ldc, K, ct, st, vt);
}

// merged GEMM2 (work 0..319) + GEMM3 (work 320..1087), XCD-swizzled
__global__ __launch_bounds__(256) void k_gemm23(const bf16* __restrict__ C1,
                                                const bf16* __restrict__ BT2,
                                                const bf16* __restrict__ BT3,
                                                bf16* __restrict__ KA,
                                                bf16* __restrict__ QA,
                                                bf16* __restrict__ VT,
                                                const float* __restrict__ ct,
                                                const float* __restrict__ st) {
    __shared__ __align__(16) bf16 As[2][128 * 32];
    __shared__ __align__(16) bf16 Bs[2][128 * 32];
    const int id = xcd_swz(blockIdx.x, 1088);
    if (id < 320) {
        gemm_body<2>(As, Bs, id % 10, id / 10, C1, 2048, BT2, 512, KA, 0, 512, ct, st, VT);
    } else {
        const int b2 = id - 320;
        gemm_body<3>(As, Bs, b2 % 24, b2 / 24, C1 + 512, 2048, BT3, 1536, QA, 0, 1536,
                     ct, st, nullptr);
    }
}

// ---------------- causal GQA flash attention (R7-validated design) ------------
// grid (16, B*H); 4 waves x 32 q-rows = 128 q-rows/block; 64-key tiles.
// S^T = mfma(K, Q): col=q (lane&15), row=key -> per-lane scalar softmax state.
// O^T = mfma(V^T, P^T): col=q, row=d.
// Fixed-shift softmax: P = exp(S) directly (shift-invariance; |S|~O(1),
// masked S=-1e30 -> P=0). K/V LDS linear rows + 16B-chunk XOR swizzle via
// pre-swizzled global source (rule #21). P via per-wave Plds (validated:
// VGPR=128, no scratch — P-in-register variants demoted to scratch, R9/R10).
__global__ __launch_bounds__(256, 2) void k_attn(const bf16* __restrict__ qa,
                                                 const bf16* __restrict__ ka,
                                                 const bf16* __restrict__ vt,
                                                 bf16* __restrict__ out) {
    __shared__ __align__(16) bf16 Klds[64 * QK_DIM];
    __shared__ __align__(16) bf16 Vlds[128 * 64];
    __shared__ __align__(16) bf16 Plds[4][32 * 64];

    const int tid  = threadIdx.x;
    const int lane = tid & 63;
    const int wid  = tid >> 6;
    const int g = lane >> 4, c = lane & 15;
    const int hsw = c & 7;                 // chunk-xor swizzle key

    // pair tile i with 15-i across the (id, id+256) CU co-residents
    const int qi = (blockIdx.y & 16) ? (15 - (int)blockIdx.x) : (int)blockIdx.x;
    const int q0 = qi * 128;
    const int bh = blockIdx.y;
    const int b = bh >> 4, h = bh & 15;
    const int kv = b * NKV + (h >> 2);
    const int qb0 = q0 + wid * 32;

    // Q B-fragments (already scaled by 1/sqrt(192)): qf[qs][cc]
    bf16x8 qf[2][6];
    #pragma unroll
    for (int qs = 0; qs < 2; ++qs) {
        const bf16* qp = qa + ((size_t)bh * TT + qb0 + qs * 16 + c) * QK_DIM + g * 8;
        #pragma unroll
        for (int cc = 0; cc < 6; ++cc) qf[qs][cc] = *(const bf16x8*)(qp + cc * 32);
    }

    f32x4 accO[2][8] = {};
    float l[2] = {0.f, 0.f};

    const bf16* kbase = ka + (size_t)kv * TT * QK_DIM;
    const bf16* vbase = vt + (size_t)kv * V_DIM * TT;

    const int nk = 2 * qi + 2;
    for (int it = 0; it < nk; ++it) {
        const int k0 = it * 64;
        __syncthreads();
        // stage K tile [64][192]: 1536 16B-chunks, source pre-swizzled
        #pragma unroll
        for (int i = 0; i < 6; ++i) {
            int ch = tid + 256 * i;
            int row = ch / 24, cs = ch % 24;
            int gc = cs ^ (row & 7);
            gload16(kbase + (size_t)(k0 + row) * QK_DIM + gc * 8, &Klds[ch * 8]);
        }
        // stage V^T tile [128][64]: 1024 chunks
        #pragma unroll
        for (int i = 0; i < 4; ++i) {
            int ch = tid + 256 * i;
            int row = ch >> 3, cs = ch & 7;
            int gc = cs ^ (row & 7);
            gload16(vbase + (size_t)row * TT + k0 + gc * 8, &Vlds[ch * 8]);
        }
        __syncthreads();

        if (k0 > qb0 + 15) continue;          // whole wave masked this tile
        const bool a1 = (k0 <= qb0 + 31);     // qs=1 active (a1 => a0)

        // S^T = K * Q^T : s[qs][j], key = k0 + j*16 + g*4 + r, q = qb0+qs*16+c
        f32x4 s[2][4] = {};
        #pragma unroll
        for (int cc = 0; cc < 6; ++cc) {
            #pragma unroll
            for (int j = 0; j < 4; ++j) {
                bf16x8 kf = *(const bf16x8*)&Klds[(j * 16 + c) * QK_DIM +
                                                  ((4 * cc + g) ^ hsw) * 8];
                s[0][j] = __builtin_amdgcn_mfma_f32_16x16x32_bf16(kf, qf[0][cc], s[0][j], 0, 0, 0);
                s[1][j] = __builtin_amdgcn_mfma_f32_16x16x32_bf16(kf, qf[1][cc], s[1][j], 0, 0, 0);
            }
        }

        // fixed-shift softmax per q-subtile: P = exp(S), l += sum(P)
        #pragma unroll
        for (int qs = 0; qs < 2; ++qs) {
            if (qs == 1 && !a1) break;
            const int qb = qb0 + qs * 16;
            if (k0 + 63 > qb) {               // diagonal: apply causal mask
                #pragma unroll
                for (int j = 0; j < 4; ++j)
                    #pragma unroll
                    for (int r = 0; r < 4; ++r)
                        if (k0 + j * 16 + g * 4 + r > qb + c) s[qs][j][r] = -1e30f;
            }
            float ps = 0.f;
            #pragma unroll
            for (int j = 0; j < 4; ++j) {
                bf16x4 pk;
                #pragma unroll
                for (int r = 0; r < 4; ++r) {
                    float e = __expf(s[qs][j][r]);
                    ps += e;
                    pk[r] = (bf16)e;
                }
                // packed P^T write: row=q (qs*16+c), keys j*16+g*4..+3, swizzled
                *(bf16x4*)&Plds[wid][(qs * 16 + c) * 64 +
                                     ((j * 16 + g * 4) ^ (hsw * 8))] = pk;
            }
            ps += __shfl_xor(ps, 16, 64);
            ps += __shfl_xor(ps, 32, 64);
            l[qs] += ps;
        }

        // O^T += V^T * P^T  (vf shared across both q-subtiles)
        if (a1) {
            #pragma unroll
            for (int kc = 0; kc < 2; ++kc) {
                bf16x8 pf0 = *(const bf16x8*)&Plds[wid][(c)      * 64 + ((kc * 32 + g * 8) ^ (hsw * 8))];
                bf16x8 pf1 = *(const bf16x8*)&Plds[wid][(16 + c) * 64 + ((kc * 32 + g * 8) ^ (hsw * 8))];
                #pragma unroll
                for (int nj = 0; nj < 8; ++nj) {
                    bf16x8 vf = *(const bf16x8*)&Vlds[(nj * 16 + c) * 64 +
                                                      ((4 * kc + g) ^ hsw) * 8];
                    accO[0][nj] = __builtin_amdgcn_mfma_f32_16x16x32_bf16(vf, pf0, accO[0][nj], 0, 0, 0);
                    accO[1][nj] = __builtin_amdgcn_mfma_f32_16x16x32_bf16(vf, pf1, accO[1][nj], 0, 0, 0);
                }
            }
        } else {
            #pragma unroll
            for (int kc = 0; kc < 2; ++kc) {
                bf16x8 pf0 = *(const bf16x8*)&Plds[wid][(c) * 64 + ((kc * 32 + g * 8) ^ (hsw * 8))];
                #pragma unroll
                for (int nj = 0; nj < 8; ++nj) {
                    bf16x8 vf = *(const bf16x8*)&Vlds[(nj * 16 + c) * 64 +
                                                      ((4 * kc + g) ^ hsw) * 8];
                    accO[0][nj] = __builtin_amdgcn_mfma_f32_16x16x32_bf16(vf, pf0, accO[0][nj], 0, 0, 0);
                }
            }
        }
    }

    // epilogue: out[b*T+q][h*128 + d], d = nj*16 + g*4 + r, q = qb0+qs*16+c
    #pragma unroll
    for (int qs = 0; qs < 2; ++qs) {
        float inv = 1.f / l[qs];
        size_t rowoff = ((size_t)(b * TT + qb0 + qs * 16 + c)) * (NH * V_DIM) + h * V_DIM;
        #pragma unroll
        for (int nj = 0; nj < 8; ++nj) {
            bf16x4 o;
            #pragma unroll
            for (int r = 0; r < 4; ++r) o[r] = (bf16)(accO[qs][nj][r] * inv);
            *(bf16x4*)&out[rowoff + nj * 16 + g * 4] = o;
        }
    }
}

// ------------------------------------------------------------------
extern "C" void kernel_launch(void* const* d_in, const int* in_sizes, int n_in,
                              void* d_out, int out_size, void* d_ws, size_t ws_size,
                              hipStream_t stream) {
    const float* x    = (const float*)d_in[0];

    char* p = (char*)d_ws;
    size_t off = 0;
    auto take = [&](size_t elems, size_t esz) -> void* {
        void* r = p + off;
        off += ((elems * esz + 255) / 256) * 256;
        return r;
    };

    bf16* XB  = (bf16*)take((size_t)MM * 2048, 2);       // x bf16
    bf16* BT1 = (bf16*)take((size_t)2048 * 2048, 2);     // [kv_down^T ; q_down^T]
    bf16* BT2 = (bf16*)take((size_t)1280 * 512, 2);      // [k_nope^T ; k_rope^T ; v^T]
    bf16* BT3 = (bf16*)take((size_t)3072 * 1536, 2);     // [q_nope^T ; q_rope^T]
    bf16* BTO = (bf16*)take((size_t)2048 * 2048, 2);     // W_o^T
    bf16* C1  = (bf16*)take((size_t)MM * 2048, 2);       // [kv_c | q_c]
    bf16* QA  = (bf16*)take((size_t)BB * NH * TT * QK_DIM, 2);
    bf16* KA  = (bf16*)take((size_t)BB * NKV * TT * QK_DIM, 2);
    bf16* VT  = (bf16*)take((size_t)BB * NKV * V_DIM * TT, 2);
    bf16* AO  = (bf16*)take((size_t)MM * 2048, 2);       // attention out
    float* CT = (float*)take((size_t)TT * 32, 4);
    float* ST = (float*)take((size_t)TT * 32, 4);
    (void)ws_size; (void)in_sizes; (void)n_in; (void)out_size;

    // --- stage 0: one fused prep kernel ---
    PrepArgs pa;
    pa.wsrc[0] = (const float*)d_in[1]; pa.wdst[0] = BT1;                         // Wkvd
    pa.wsrc[1] = (const float*)d_in[5]; pa.wdst[1] = BT1 + (size_t)512 * 2048;    // Wqd
    pa.wsrc[2] = (const float*)d_in[2]; pa.wdst[2] = BT2;                         // Wkn
    pa.wsrc[3] = (const float*)d_in[3]; pa.wdst[3] = BT2 + (size_t)512 * 512;     // Wkr
    pa.wsrc[4] = (const float*)d_in[4]; pa.wdst[4] = BT2 + (size_t)768 * 512;     // Wv
    pa.wsrc[5] = (const float*)d_in[6]; pa.wdst[5] = BT3;                         // Wqn
    pa.wsrc[6] = (const float*)d_in[7]; pa.wdst[6] = BT3 + (size_t)2048 * 1536;   // Wqr
    pa.wsrc[7] = (const float*)d_in[8]; pa.wdst[7] = BTO;                         // Wo
    pa.x = x; pa.xb = XB; pa.ct = CT; pa.st = ST;
    k_prep<<<21888, 256, 0, stream>>>(pa);

    // --- stage 1: projection GEMMs (RoPE/assembly fused into epilogues) ---
    k_gemm<0><<<512, 256, 0, stream>>>(XB, 2048, BT1, 2048, C1, 2048, 2048,
                                       nullptr, nullptr, nullptr, 16, 512);
    k_gemm23<<<1088, 256, 0, stream>>>(C1, BT2, BT3, KA, QA, VT, CT, ST);

    // --- stage 2: causal GQA flash attention ---
    k_attn<<<dim3(16, BB * NH), 256, 0, stream>>>(QA, KA, VT, AO);

    // --- stage 3: output projection (f32 out) ---
    k_gemm<1><<<512, 256, 0, stream>>>(AO, 2048, BTO, 2048, d_out, 2048, 2048,
                                       nullptr, nullptr, nullptr, 16, 512);
}